// Round 4
// baseline (146.183 us; speedup 1.0000x reference)
//
#include <hip/hip_runtime.h>
#include <math.h>

// Problem constants (B=1)
#define S 2048
#define DM 512
#define WIN 64
#define ATTN_SCALE 0.17677669529663687f   // 1/sqrt(32)

typedef __attribute__((ext_vector_type(8))) short short8;   // 8 x bf16
typedef __attribute__((ext_vector_type(4))) float floatx4;  // MFMA acc

// Pack two fp32 -> two bf16 (round-half-up, ~1/2 ULP) in one dword.
__device__ __forceinline__ unsigned int pack_bf16_rh(float f0, float f1) {
  unsigned int u0 = __float_as_uint(f0) + 0x8000u;
  unsigned int u1 = __float_as_uint(f1) + 0x8000u;
  // result bytes: [u1.b3, u1.b2, u0.b3, u0.b2] = (bf1<<16)|bf0
  return __builtin_amdgcn_perm(u1, u0, 0x07060302u);
}

// ---------------------------------------------------------------------------
// MFMA GEMM, fp32 in / fp32 out, bf16 compute:
//   C_z[M,N] = A[M,K] * B_z[N,K]^T   (both row-major, K contiguous)
// 128x128 block tile, BK=64, 256 threads = 4 waves (2x2), wave tile 64x64
// via 4x4 of mfma_f32_16x16x32_bf16. fp32->bf16 conversion fused into LDS
// staging. LDS 16B-granule XOR swizzle: granule g of row r at slot g^(r&7)
// -> MFMA-frag reads 2-way (free), staging writes phase-balanced.
// blockIdx.z selects B operand / C plane (fused QKV).
// ---------------------------------------------------------------------------
__global__ __launch_bounds__(256) void gemm_mfma(
    const float* __restrict__ A,
    const float* __restrict__ B0, const float* __restrict__ B1,
    const float* __restrict__ B2,
    float* __restrict__ Cbase, int cstride,
    int M, int N, int K) {
  __shared__ unsigned short As[128 * 64];   // 16 KB
  __shared__ unsigned short Bs[128 * 64];   // 16 KB

  const int z = blockIdx.z;
  const float* Bp = (z == 0) ? B0 : (z == 1) ? B1 : B2;
  float* C = Cbase + (size_t)z * cstride;

  const int row0 = blockIdx.y * 128;
  const int col0 = blockIdx.x * 128;
  const int tid  = threadIdx.x;
  const int lane = tid & 63;
  const int w    = tid >> 6;       // wave 0..3
  const int wr   = w >> 1;         // wave row 0..1
  const int wc   = w & 1;          // wave col 0..1
  const int quad = lane >> 4;      // 0..3
  const int lc   = lane & 15;

  // staging: thread -> (row srow 0..127, k-half shalf covering 32 floats)
  const int srow  = tid >> 1;
  const int shalf = tid & 1;
  const int s7    = srow & 7;
  const float* ga = A  + (size_t)(row0 + srow) * K + shalf * 32;
  const float* gb = Bp + (size_t)(col0 + srow) * K + shalf * 32;
  unsigned short* asw = &As[srow * 64];
  unsigned short* bsw = &Bs[srow * 64];

  floatx4 acc[4][4] = {};

  for (int k0 = 0; k0 < K; k0 += 64) {
    uint4 ua[4], ub[4];
#pragma unroll
    for (int g = 0; g < 4; ++g) {
      float4 f0 = *(const float4*)(ga + k0 + g * 8);
      float4 f1 = *(const float4*)(ga + k0 + g * 8 + 4);
      ua[g].x = pack_bf16_rh(f0.x, f0.y);
      ua[g].y = pack_bf16_rh(f0.z, f0.w);
      ua[g].z = pack_bf16_rh(f1.x, f1.y);
      ua[g].w = pack_bf16_rh(f1.z, f1.w);
    }
#pragma unroll
    for (int g = 0; g < 4; ++g) {
      float4 f0 = *(const float4*)(gb + k0 + g * 8);
      float4 f1 = *(const float4*)(gb + k0 + g * 8 + 4);
      ub[g].x = pack_bf16_rh(f0.x, f0.y);
      ub[g].y = pack_bf16_rh(f0.z, f0.w);
      ub[g].z = pack_bf16_rh(f1.x, f1.y);
      ub[g].w = pack_bf16_rh(f1.z, f1.w);
    }
    __syncthreads();   // previous iteration's LDS reads complete
#pragma unroll
    for (int g = 0; g < 4; ++g) {
      const int slot = (shalf * 4 + g) ^ s7;
      *(uint4*)&asw[slot * 8] = ua[g];
      *(uint4*)&bsw[slot * 8] = ub[g];
    }
    __syncthreads();

#pragma unroll
    for (int s = 0; s < 2; ++s) {
      const int gk = s * 4 + quad;            // k-granule 0..7
      short8 aF[4], bF[4];
#pragma unroll
      for (int i = 0; i < 4; ++i) {
        const int m = wr * 64 + i * 16 + lc;
        aF[i] = *(const short8*)&As[m * 64 + ((gk ^ (m & 7)) * 8)];
      }
#pragma unroll
      for (int j = 0; j < 4; ++j) {
        const int n = wc * 64 + j * 16 + lc;
        bF[j] = *(const short8*)&Bs[n * 64 + ((gk ^ (n & 7)) * 8)];
      }
#pragma unroll
      for (int i = 0; i < 4; ++i)
#pragma unroll
        for (int j = 0; j < 4; ++j)
          acc[i][j] = __builtin_amdgcn_mfma_f32_16x16x32_bf16(
              aF[i], bF[j], acc[i][j], 0, 0, 0);
    }
  }

  // C/D layout: col = lane&15, row = quad*4 + reg  [verified m89/m91]
#pragma unroll
  for (int i = 0; i < 4; ++i)
#pragma unroll
    for (int j = 0; j < 4; ++j) {
      const int col = col0 + wc * 64 + j * 16 + lc;
#pragma unroll
      for (int r = 0; r < 4; ++r) {
        const int row = row0 + wr * 64 + i * 16 + quad * 4 + r;
        C[(size_t)row * N + col] = acc[i][j][r];
      }
    }
}

// ---------------------------------------------------------------------------
// Sliding-window per-channel softmax, R=4 row blocking.
// Thread owns rows i0..i0+3 at channel c; k/v window loads shared across the
// 4 rows (L2 traffic /4). Shift-invariant softmax (|s|<~6, exp safe in fp32).
// Validity: j>=0 and (unsigned)(i0+r-j) < 64  <=>  i0+r-63 <= j <= i0+r.
// i0 is block-uniform (256 threads = half a channel-row) -> no divergence.
// ---------------------------------------------------------------------------
__global__ __launch_bounds__(256) void swin_attn4(
    const float* __restrict__ q, const float* __restrict__ k,
    const float* __restrict__ v, float* __restrict__ o) {
  const int gid = blockIdx.x * 256 + threadIdx.x;
  const int c = gid & 511;
  const int i0 = (gid >> 9) * 4;

  float qs[4], l[4], a[4];
#pragma unroll
  for (int r = 0; r < 4; ++r) {
    qs[r] = q[(size_t)(i0 + r) * DM + c] * ATTN_SCALE;
    l[r] = 0.f;
    a[r] = 0.f;
  }

  for (int j = i0 - (WIN - 1); j <= i0 + 3; ++j) {
    const int jc = j < 0 ? 0 : j;
    const float kv = k[(size_t)jc * DM + c];
    const float vv = v[(size_t)jc * DM + c];
#pragma unroll
    for (int r = 0; r < 4; ++r) {
      const bool valid = (j >= 0) & ((unsigned)(i0 + r - j) < 64u);
      float p = __expf(qs[r] * kv);
      p = valid ? p : 0.f;
      l[r] += p;
      a[r] = fmaf(p, vv, a[r]);
    }
  }
#pragma unroll
  for (int r = 0; r < 4; ++r)
    o[(size_t)(i0 + r) * DM + c] = a[r] / l[r];
}

// ---------------------------------------------------------------------------
// Launch: 3 dispatches (fused QKV gemm, attn, out-proj gemm).
// ---------------------------------------------------------------------------
extern "C" void kernel_launch(void* const* d_in, const int* in_sizes, int n_in,
                              void* d_out, int out_size, void* d_ws, size_t ws_size,
                              hipStream_t stream) {
  const float* x  = (const float*)d_in[0];
  const float* Wq = (const float*)d_in[1];
  const float* Wk = (const float*)d_in[2];
  const float* Wv = (const float*)d_in[3];
  const float* Wo = (const float*)d_in[4];
  float* out = (float*)d_out;

  // ws: q, k, v, attn -- 4 x S*DM fp32 = 16 MB
  float* q    = (float*)d_ws;
  float* kk   = q  + (size_t)S * DM;
  float* vv   = kk + (size_t)S * DM;
  float* attn = vv + (size_t)S * DM;

  // 1) fused QKV: {q,k,v}_z = x * W_z^T
  gemm_mfma<<<dim3(DM / 128, S / 128, 3), dim3(256), 0, stream>>>(
      x, Wq, Wk, Wv, q, S * DM, S, DM, DM);

  // 2) sliding-window per-channel softmax
  swin_attn4<<<dim3(S * DM / 1024), dim3(256), 0, stream>>>(q, kk, vv, attn);

  // 3) output projection: out = attn * Wo^T
  gemm_mfma<<<dim3(DM / 128, S / 128, 1), dim3(256), 0, stream>>>(
      attn, Wo, Wo, Wo, out, 0, S, DM, DM);
}

// Round 5
// 144.873 us; speedup vs baseline: 1.0090x; 1.0090x over previous
//
#include <hip/hip_runtime.h>
#include <math.h>

// Problem constants (B=1)
#define S 2048
#define DM 512
#define WIN 64
#define ATTN_SCALE 0.17677669529663687f   // 1/sqrt(32)

typedef __attribute__((ext_vector_type(8))) short short8;   // 8 x bf16
typedef __attribute__((ext_vector_type(4))) float floatx4;  // MFMA acc

__device__ __forceinline__ unsigned short f2bf(float f) {
  unsigned int u = __float_as_uint(f);
  return (unsigned short)((u + 0x7FFFu + ((u >> 16) & 1u)) >> 16);   // RNE
}

// ---------------------------------------------------------------------------
// Convert x (S*DM floats) and Wq|Wk|Wv|Wo (4 * DM*DM) to bf16.
// ---------------------------------------------------------------------------
__global__ __launch_bounds__(256) void convert_bf16(
    const float* __restrict__ x, const float* __restrict__ Wq,
    const float* __restrict__ Wk, const float* __restrict__ Wv,
    const float* __restrict__ Wo,
    unsigned short* __restrict__ xbf, unsigned short* __restrict__ wbf) {
  size_t i4 = ((size_t)blockIdx.x * 256 + threadIdx.x) * 4;
  const float* src; unsigned short* dst; size_t off;
  const size_t NX = (size_t)S * DM;           // 1,048,576
  if (i4 < NX) {
    src = x; dst = xbf; off = i4;
  } else {
    size_t r = i4 - NX;
    int wsel = (int)(r >> 18);                // / (512*512)
    src = wsel == 0 ? Wq : wsel == 1 ? Wk : wsel == 2 ? Wv : Wo;
    dst = wbf + ((size_t)wsel << 18);
    off = r & 262143;
  }
  float4 f = *(const float4*)(src + off);
  ushort4 o;
  o.x = f2bf(f.x); o.y = f2bf(f.y); o.z = f2bf(f.z); o.w = f2bf(f.w);
  *(ushort4*)(dst + off) = o;
}

// ---------------------------------------------------------------------------
// bf16 MFMA GEMM: C[M,N] = A[M,K] * B[N,K]^T  (fp32 out). BK=64, 256 thr =
// 4 waves (2x2), wave tile (BM/2)x(BN/2) via (BM/32)x(BN/32) 16x16x32 MFMAs.
// Staging: thread (trow=tid>>3, tg=tid&7) loads granule tg of rows
// u*32+trow -> each load instr is a contiguous 1KB wave read.
// LDS XOR swizzle: granule g of row r at slot g^(r&7) -> ds_write and
// ds_read both spread 8 lanes per 4-bank group (phase-balanced).
// blockIdx.z selects B operand / C plane (fused QKV).
// ---------------------------------------------------------------------------
template <int BM, int BN>
__global__ __launch_bounds__(256) void gemm_bf16(
    const unsigned short* __restrict__ Abf,
    const unsigned short* __restrict__ Bbase, int bstride,
    float* __restrict__ Cbase, int cstride, int N, int K) {
  constexpr int MI = BM / 32;
  constexpr int NJ = BN / 32;
  __shared__ unsigned short As[BM * 64];
  __shared__ unsigned short Bs[BN * 64];

  const unsigned short* Bp = Bbase + (size_t)blockIdx.z * bstride;
  float* C = Cbase + (size_t)blockIdx.z * cstride;

  const int row0 = blockIdx.y * BM;
  const int col0 = blockIdx.x * BN;
  const int tid  = threadIdx.x;
  const int lane = tid & 63;
  const int w    = tid >> 6;
  const int wr   = w >> 1;
  const int wc   = w & 1;
  const int quad = lane >> 4;
  const int lc   = lane & 15;
  const int trow = tid >> 3;                    // 0..31
  const int tg   = tid & 7;                     // granule 0..7
  const int tslot = (tg ^ (trow & 7)) * 8;      // swizzled elem offset

  floatx4 acc[MI][NJ] = {};

  for (int k0 = 0; k0 < K; k0 += 64) {
    uint4 ua[MI], ub[NJ];
#pragma unroll
    for (int u = 0; u < MI; ++u)
      ua[u] = *(const uint4*)&Abf[(size_t)(row0 + u * 32 + trow) * K + k0 + tg * 8];
#pragma unroll
    for (int u = 0; u < NJ; ++u)
      ub[u] = *(const uint4*)&Bp[(size_t)(col0 + u * 32 + trow) * K + k0 + tg * 8];
    __syncthreads();   // previous iteration's LDS reads complete
#pragma unroll
    for (int u = 0; u < MI; ++u)
      *(uint4*)&As[(u * 32 + trow) * 64 + tslot] = ua[u];
#pragma unroll
    for (int u = 0; u < NJ; ++u)
      *(uint4*)&Bs[(u * 32 + trow) * 64 + tslot] = ub[u];
    __syncthreads();

#pragma unroll
    for (int s = 0; s < 2; ++s) {
      const int gk = s * 4 + quad;              // k-granule 0..7
      short8 aF[MI], bF[NJ];
#pragma unroll
      for (int i = 0; i < MI; ++i) {
        const int m = wr * (BM / 2) + i * 16 + lc;
        aF[i] = *(const short8*)&As[m * 64 + (gk ^ (m & 7)) * 8];
      }
#pragma unroll
      for (int j = 0; j < NJ; ++j) {
        const int n = wc * (BN / 2) + j * 16 + lc;
        bF[j] = *(const short8*)&Bs[n * 64 + (gk ^ (n & 7)) * 8];
      }
#pragma unroll
      for (int i = 0; i < MI; ++i)
#pragma unroll
        for (int j = 0; j < NJ; ++j)
          acc[i][j] = __builtin_amdgcn_mfma_f32_16x16x32_bf16(
              aF[i], bF[j], acc[i][j], 0, 0, 0);
    }
  }

  // C/D layout: col = lane&15, row = quad*4 + reg  [verified m89/m91]
#pragma unroll
  for (int i = 0; i < MI; ++i)
#pragma unroll
    for (int j = 0; j < NJ; ++j) {
      const int col = col0 + wc * (BN / 2) + j * 16 + lc;
#pragma unroll
      for (int r = 0; r < 4; ++r) {
        const int row = row0 + wr * (BM / 2) + i * 16 + quad * 4 + r;
        C[(size_t)row * N + col] = acc[i][j][r];
      }
    }
}

// ---------------------------------------------------------------------------
// Sliding-window per-channel softmax, R=4 row blocking, bf16 output.
// Thread owns rows i0..i0+3 at channel c; k/v window loads shared across the
// 4 rows. Shift-invariant softmax (|s|<~6, fp32 exp safe).
// i0 is block-uniform -> no divergence on the row loop bounds.
// ---------------------------------------------------------------------------
__global__ __launch_bounds__(256) void swin_attn4(
    const float* __restrict__ q, const float* __restrict__ k,
    const float* __restrict__ v, unsigned short* __restrict__ o) {
  const int gid = blockIdx.x * 256 + threadIdx.x;
  const int c = gid & 511;
  const int i0 = (gid >> 9) * 4;

  float qs[4], l[4], a[4];
#pragma unroll
  for (int r = 0; r < 4; ++r) {
    qs[r] = q[(size_t)(i0 + r) * DM + c] * ATTN_SCALE;
    l[r] = 0.f;
    a[r] = 0.f;
  }

  for (int j = i0 - (WIN - 1); j <= i0 + 3; ++j) {
    const int jc = j < 0 ? 0 : j;
    const float kv = k[(size_t)jc * DM + c];
    const float vv = v[(size_t)jc * DM + c];
#pragma unroll
    for (int r = 0; r < 4; ++r) {
      const bool valid = (j >= 0) & ((unsigned)(i0 + r - j) < 64u);
      float p = __expf(qs[r] * kv);
      p = valid ? p : 0.f;
      l[r] += p;
      a[r] = fmaf(p, vv, a[r]);
    }
  }
#pragma unroll
  for (int r = 0; r < 4; ++r)
    o[(size_t)(i0 + r) * DM + c] = f2bf(a[r] / l[r]);
}

// ---------------------------------------------------------------------------
// Launch: convert, fused QKV gemm (384 blocks), attn, out-proj gemm (256).
// ---------------------------------------------------------------------------
extern "C" void kernel_launch(void* const* d_in, const int* in_sizes, int n_in,
                              void* d_out, int out_size, void* d_ws, size_t ws_size,
                              hipStream_t stream) {
  const float* x  = (const float*)d_in[0];
  const float* Wq = (const float*)d_in[1];
  const float* Wk = (const float*)d_in[2];
  const float* Wv = (const float*)d_in[3];
  const float* Wo = (const float*)d_in[4];
  float* out = (float*)d_out;

  // ws layout (16 MB): q,k,v fp32 (12 MB); xbf 2 MB (reused as attn bf16);
  // wbf 4 planes 2 MB.
  float* q  = (float*)d_ws;
  float* kk = q  + (size_t)S * DM;
  float* vv = kk + (size_t)S * DM;
  unsigned short* xbf = (unsigned short*)(vv + (size_t)S * DM);
  unsigned short* wbf = xbf + (size_t)S * DM;
  unsigned short* attnbf = xbf;   // safe: attn runs after QKV consumed xbf

  // 1) fp32 -> bf16 (x and all four W)
  convert_bf16<<<dim3(2048), dim3(256), 0, stream>>>(x, Wq, Wk, Wv, Wo, xbf, wbf);

  // 2) fused QKV: {q,k,v}_z = x * W_z^T   (128x64 tiles, 384 blocks)
  gemm_bf16<128, 64><<<dim3(DM / 64, S / 128, 3), dim3(256), 0, stream>>>(
      xbf, wbf, DM * DM, q, S * DM, DM, DM);

  // 3) sliding-window per-channel softmax -> bf16
  swin_attn4<<<dim3(S * DM / 1024), dim3(256), 0, stream>>>(q, kk, vv, attnbf);

  // 4) output projection: out = attn * Wo^T   (64x64 tiles, 256 blocks)
  gemm_bf16<64, 64><<<dim3(DM / 64, S / 64, 1), dim3(256), 0, stream>>>(
      attnbf, wbf + 3 * (size_t)DM * DM, 0, out, 0, DM, DM);
}

// Round 6
// 130.967 us; speedup vs baseline: 1.1162x; 1.1062x over previous
//
#include <hip/hip_runtime.h>
#include <math.h>

// Problem constants (B=1)
#define S 2048
#define DM 512
#define WIN 64
#define ATTN_SCALE 0.17677669529663687f   // 1/sqrt(32)

typedef __attribute__((ext_vector_type(8))) short short8;   // 8 x bf16
typedef __attribute__((ext_vector_type(4))) float floatx4;  // MFMA acc

// Pack two fp32 -> (bf1<<16)|bf0, round-half-up (HW-verified in R4).
__device__ __forceinline__ unsigned int pack_bf16_rh(float f0, float f1) {
  unsigned int u0 = __float_as_uint(f0) + 0x8000u;
  unsigned int u1 = __float_as_uint(f1) + 0x8000u;
  return __builtin_amdgcn_perm(u1, u0, 0x07060302u);
}
__device__ __forceinline__ unsigned short f2bf(float f) {
  return (unsigned short)((__float_as_uint(f) + 0x8000u) >> 16);
}

// ---------------------------------------------------------------------------
// Fused QKV GEMM, fp32 inputs, bf16 outputs:
//   {q|k|v}[M,N](bf16) = x[M,K] * W_z[N,K]^T,  z = blockIdx.z
// 64x64 tile, BK=64, 256 thr = 4 waves (2x2), wave tile 32x32 via 2x2 of
// mfma_f32_16x16x32_bf16. fp32->bf16 pack fused into LDS staging.
// LDS XOR swizzle: 16B granule g of row r at slot g^(r&7) (R3-verified).
// Grid 8x32x3 = 768 blocks = 3/CU, the known-good occupancy point.
// ---------------------------------------------------------------------------
__global__ __launch_bounds__(256) void gemm_qkv(
    const float* __restrict__ A,
    const float* __restrict__ B0, const float* __restrict__ B1,
    const float* __restrict__ B2,
    unsigned short* __restrict__ Cb) {
  __shared__ unsigned short As[64 * 64];
  __shared__ unsigned short Bs[64 * 64];

  const int z = blockIdx.z;
  const float* Bp = (z == 0) ? B0 : (z == 1) ? B1 : B2;
  unsigned short* C = Cb + (size_t)z * (S * DM);

  const int row0 = blockIdx.y * 64;
  const int col0 = blockIdx.x * 64;
  const int tid  = threadIdx.x;
  const int lane = tid & 63;
  const int w    = tid >> 6;
  const int wr   = w >> 1;
  const int wc   = w & 1;
  const int quad = lane >> 4;
  const int lc   = lane & 15;
  const int trow = tid >> 3;                 // 0..31
  const int tg   = tid & 7;                  // granule 0..7
  const int tslot = (tg ^ (trow & 7)) * 8;

  floatx4 acc[2][2] = {};

  for (int k0 = 0; k0 < DM; k0 += 64) {
    uint4 ua[2], ub[2];
#pragma unroll
    for (int u = 0; u < 2; ++u) {
      const float* pa = &A[(size_t)(row0 + u * 32 + trow) * DM + k0 + tg * 8];
      float4 f0 = *(const float4*)pa;
      float4 f1 = *(const float4*)(pa + 4);
      ua[u].x = pack_bf16_rh(f0.x, f0.y); ua[u].y = pack_bf16_rh(f0.z, f0.w);
      ua[u].z = pack_bf16_rh(f1.x, f1.y); ua[u].w = pack_bf16_rh(f1.z, f1.w);
      const float* pb = &Bp[(size_t)(col0 + u * 32 + trow) * DM + k0 + tg * 8];
      float4 g0 = *(const float4*)pb;
      float4 g1 = *(const float4*)(pb + 4);
      ub[u].x = pack_bf16_rh(g0.x, g0.y); ub[u].y = pack_bf16_rh(g0.z, g0.w);
      ub[u].z = pack_bf16_rh(g1.x, g1.y); ub[u].w = pack_bf16_rh(g1.z, g1.w);
    }
    __syncthreads();   // previous iteration's LDS reads complete
#pragma unroll
    for (int u = 0; u < 2; ++u) {
      *(uint4*)&As[(u * 32 + trow) * 64 + tslot] = ua[u];
      *(uint4*)&Bs[(u * 32 + trow) * 64 + tslot] = ub[u];
    }
    __syncthreads();

#pragma unroll
    for (int s = 0; s < 2; ++s) {
      const int gk = s * 4 + quad;
      short8 aF[2], bF[2];
#pragma unroll
      for (int i = 0; i < 2; ++i) {
        const int m = wr * 32 + i * 16 + lc;
        aF[i] = *(const short8*)&As[m * 64 + (gk ^ (m & 7)) * 8];
      }
#pragma unroll
      for (int j = 0; j < 2; ++j) {
        const int n = wc * 32 + j * 16 + lc;
        bF[j] = *(const short8*)&Bs[n * 64 + (gk ^ (n & 7)) * 8];
      }
#pragma unroll
      for (int i = 0; i < 2; ++i)
#pragma unroll
        for (int j = 0; j < 2; ++j)
          acc[i][j] = __builtin_amdgcn_mfma_f32_16x16x32_bf16(
              aF[i], bF[j], acc[i][j], 0, 0, 0);
    }
  }

  // C/D layout: col = lane&15, row = quad*4 + reg  [verified m89/m91]
#pragma unroll
  for (int i = 0; i < 2; ++i)
#pragma unroll
    for (int j = 0; j < 2; ++j) {
      const int col = col0 + wc * 32 + j * 16 + lc;
#pragma unroll
      for (int r = 0; r < 4; ++r) {
        const int row = row0 + wr * 32 + i * 16 + quad * 4 + r;
        C[(size_t)row * DM + col] = f2bf(acc[i][j][r]);
      }
    }
}

// ---------------------------------------------------------------------------
// Output projection GEMM: out[M,N](fp32) = attn[M,K](bf16) * Wo[N,K]^T(fp32)
// Same structure; A staged directly (bf16), B pack-fused.
// ---------------------------------------------------------------------------
__global__ __launch_bounds__(256) void gemm_proj(
    const unsigned short* __restrict__ Abf, const float* __restrict__ Bw,
    float* __restrict__ C) {
  __shared__ unsigned short As[64 * 64];
  __shared__ unsigned short Bs[64 * 64];

  const int row0 = blockIdx.y * 64;
  const int col0 = blockIdx.x * 64;
  const int tid  = threadIdx.x;
  const int lane = tid & 63;
  const int w    = tid >> 6;
  const int wr   = w >> 1;
  const int wc   = w & 1;
  const int quad = lane >> 4;
  const int lc   = lane & 15;
  const int trow = tid >> 3;
  const int tg   = tid & 7;
  const int tslot = (tg ^ (trow & 7)) * 8;

  floatx4 acc[2][2] = {};

  for (int k0 = 0; k0 < DM; k0 += 64) {
    uint4 ua[2], ub[2];
#pragma unroll
    for (int u = 0; u < 2; ++u) {
      ua[u] = *(const uint4*)&Abf[(size_t)(row0 + u * 32 + trow) * DM + k0 + tg * 8];
      const float* pb = &Bw[(size_t)(col0 + u * 32 + trow) * DM + k0 + tg * 8];
      float4 g0 = *(const float4*)pb;
      float4 g1 = *(const float4*)(pb + 4);
      ub[u].x = pack_bf16_rh(g0.x, g0.y); ub[u].y = pack_bf16_rh(g0.z, g0.w);
      ub[u].z = pack_bf16_rh(g1.x, g1.y); ub[u].w = pack_bf16_rh(g1.z, g1.w);
    }
    __syncthreads();
#pragma unroll
    for (int u = 0; u < 2; ++u) {
      *(uint4*)&As[(u * 32 + trow) * 64 + tslot] = ua[u];
      *(uint4*)&Bs[(u * 32 + trow) * 64 + tslot] = ub[u];
    }
    __syncthreads();

#pragma unroll
    for (int s = 0; s < 2; ++s) {
      const int gk = s * 4 + quad;
      short8 aF[2], bF[2];
#pragma unroll
      for (int i = 0; i < 2; ++i) {
        const int m = wr * 32 + i * 16 + lc;
        aF[i] = *(const short8*)&As[m * 64 + (gk ^ (m & 7)) * 8];
      }
#pragma unroll
      for (int j = 0; j < 2; ++j) {
        const int n = wc * 32 + j * 16 + lc;
        bF[j] = *(const short8*)&Bs[n * 64 + (gk ^ (n & 7)) * 8];
      }
#pragma unroll
      for (int i = 0; i < 2; ++i)
#pragma unroll
        for (int j = 0; j < 2; ++j)
          acc[i][j] = __builtin_amdgcn_mfma_f32_16x16x32_bf16(
              aF[i], bF[j], acc[i][j], 0, 0, 0);
    }
  }

#pragma unroll
  for (int i = 0; i < 2; ++i)
#pragma unroll
    for (int j = 0; j < 2; ++j) {
      const int col = col0 + wc * 32 + j * 16 + lc;
#pragma unroll
      for (int r = 0; r < 4; ++r) {
        const int row = row0 + wr * 32 + i * 16 + quad * 4 + r;
        C[(size_t)row * DM + col] = acc[i][j][r];
      }
    }
}

// ---------------------------------------------------------------------------
// Sliding-window per-channel softmax, bf16 in/out, 2 channels per thread.
// Thread (i, c2): out[i,c] = sum_j exp(q[i,c]k[j,c]*scale) v[j,c] / sum exp,
// j in [max(0,i-63), i]. Loop trip is wave-uniform (i = gid>>8 constant per
// wave) -> no masking, no divergence. Shift-invariant softmax, |s| small.
// ---------------------------------------------------------------------------
__global__ __launch_bounds__(256) void swin_attn(
    const unsigned short* __restrict__ qkv, unsigned short* __restrict__ o) {
  const int gid = blockIdx.x * 256 + threadIdx.x;
  const int i  = gid >> 8;             // row 0..2047
  const int c2 = (gid & 255) * 2;      // channel pair

  const unsigned short* q = qkv;
  const unsigned short* k = qkv + (size_t)S * DM;
  const unsigned short* v = qkv + 2 * (size_t)S * DM;

  const unsigned int qp = *(const unsigned int*)&q[(size_t)i * DM + c2];
  const float q0 = __uint_as_float(qp << 16) * ATTN_SCALE;
  const float q1 = __uint_as_float(qp & 0xffff0000u) * ATTN_SCALE;

  float l0 = 0.f, l1 = 0.f, a0 = 0.f, a1 = 0.f;
  const int j0 = i > (WIN - 1) ? i - (WIN - 1) : 0;
  for (int j = j0; j <= i; ++j) {
    const unsigned int kp = *(const unsigned int*)&k[(size_t)j * DM + c2];
    const unsigned int vp = *(const unsigned int*)&v[(size_t)j * DM + c2];
    const float k0f = __uint_as_float(kp << 16);
    const float k1f = __uint_as_float(kp & 0xffff0000u);
    const float v0f = __uint_as_float(vp << 16);
    const float v1f = __uint_as_float(vp & 0xffff0000u);
    const float p0 = __expf(q0 * k0f);
    const float p1 = __expf(q1 * k1f);
    l0 += p0; l1 += p1;
    a0 = fmaf(p0, v0f, a0);
    a1 = fmaf(p1, v1f, a1);
  }
  *(unsigned int*)&o[(size_t)i * DM + c2] = pack_bf16_rh(a0 / l0, a1 / l1);
}

// ---------------------------------------------------------------------------
// Launch: 3 dispatches.
// ---------------------------------------------------------------------------
extern "C" void kernel_launch(void* const* d_in, const int* in_sizes, int n_in,
                              void* d_out, int out_size, void* d_ws, size_t ws_size,
                              hipStream_t stream) {
  const float* x  = (const float*)d_in[0];
  const float* Wq = (const float*)d_in[1];
  const float* Wk = (const float*)d_in[2];
  const float* Wv = (const float*)d_in[3];
  const float* Wo = (const float*)d_in[4];
  float* out = (float*)d_out;

  // ws: q|k|v bf16 planes (3 x 2 MB) + attn bf16 (2 MB) = 8 MB
  unsigned short* qkvb  = (unsigned short*)d_ws;
  unsigned short* attnb = qkvb + 3 * (size_t)S * DM;

  // 1) fused QKV with inline fp32->bf16 (768 blocks = 3/CU)
  gemm_qkv<<<dim3(DM / 64, S / 64, 3), dim3(256), 0, stream>>>(
      x, Wq, Wk, Wv, qkvb);

  // 2) sliding-window per-channel softmax (2048 blocks, 8 waves/SIMD)
  swin_attn<<<dim3(S * DM / 512), dim3(256), 0, stream>>>(qkvb, attnb);

  // 3) output projection (256 blocks)
  gemm_proj<<<dim3(DM / 64, S / 64), dim3(256), 0, stream>>>(attnb, Wo, out);
}